// Round 2
// baseline (634.072 us; speedup 1.0000x reference)
//
#include <hip/hip_runtime.h>

// ============================================================================
// Fused 2-layer transformer encoder (B=1024, T=128, D=128, H=8, HD=16, FF=512)
// One workgroup (1024 threads = 16 waves) per batch element; all activations
// resident in LDS across both layers; bf16 MFMA 16x16x32 for every matmul;
// fp32 accumulation, softmax and layernorm in fp32.
// R2: 16 waves/block (was 8) -> 4 waves/SIMD for latency hiding. Wave w owns
// column-tile ct=w>>1 and row-half mh=w&1; Phase A shares A-frags across
// q/k/v; attention P-scratch chunked to 32 keys so 16 wave-buffers fit LDS.
// ============================================================================

typedef __attribute__((ext_vector_type(8))) __bf16 bf16x8;
typedef __attribute__((ext_vector_type(4))) float fx4;

#define MFMA16(a, b, c) __builtin_amdgcn_mfma_f32_16x16x32_bf16((a), (b), (c), 0, 0, 0)

#define XS_S 136   // x buffer row stride (shorts)
#define QK_S 264   // q|k buffer row stride
#define VT_S 136   // V^T / FF-hidden row stride
#define PS_S 40    // per-wave P scratch row stride (32 keys + pad)

static __device__ __forceinline__ unsigned short f2bf(float f) {
    __bf16 b = (__bf16)f;
    return __builtin_bit_cast(unsigned short, b);
}
static __device__ __forceinline__ float bf2f(unsigned short u) {
    return (float)__builtin_bit_cast(__bf16, u);
}

// --------------------------------------------------------------------------
// Prep: fp32 weights -> bf16 in workspace, float4-vectorized.
// Segments (elements): in_proj 98304 | out 32768 | ff1 131072 | ff2 131072
// (all segment boundaries are multiples of 4)
// --------------------------------------------------------------------------
extern "C" __global__ void prep_weights_bf16(const float* __restrict__ w_in,
                                             const float* __restrict__ w_out,
                                             const float* __restrict__ w_ff1,
                                             const float* __restrict__ w_ff2,
                                             unsigned short* __restrict__ ws) {
    int i4 = blockIdx.x * 256 + threadIdx.x;     // 384 blocks -> 98304 float4s
    int i = i4 * 4;
    float4 v;
    if (i < 98304)       v = *(const float4*)(w_in + i);
    else if (i < 131072) v = *(const float4*)(w_out + (i - 98304));
    else if (i < 262144) v = *(const float4*)(w_ff1 + (i - 131072));
    else                 v = *(const float4*)(w_ff2 + (i - 262144));
    ushort4 o;
    o.x = f2bf(v.x); o.y = f2bf(v.y); o.z = f2bf(v.z); o.w = f2bf(v.w);
    *(ushort4*)(ws + i) = o;
}

// --------------------------------------------------------------------------
// Main fused kernel. block = 1024 threads = 16 waves. grid = 1024 (one per b).
// --------------------------------------------------------------------------
extern "C" __global__ void __launch_bounds__(1024)
fused_transformer(const float* __restrict__ x,
                  const float* __restrict__ mask,
                  const float* __restrict__ inp_b,
                  const float* __restrict__ out_b,
                  const float* __restrict__ ln1g, const float* __restrict__ ln1b,
                  const float* __restrict__ ff1b, const float* __restrict__ ff2b,
                  const float* __restrict__ ln2g, const float* __restrict__ ln2b,
                  const unsigned short* __restrict__ w_inp,
                  const unsigned short* __restrict__ w_out,
                  const unsigned short* __restrict__ w_ff1,
                  const unsigned short* __restrict__ w_ff2,
                  float* __restrict__ out) {
    // 154 KiB static LDS (gfx950 workgroup limit 160 KiB)
    __shared__ __align__(16) unsigned short xs[128 * XS_S];    // 34816 B
    __shared__ __align__(16) unsigned short qk[128 * QK_S];    // 67584 B
    __shared__ __align__(16) unsigned short vt[128 * VT_S];    // 34816 B
    __shared__ __align__(16) unsigned short ps[16 * 16 * PS_S];// 20480 B

    const int tid = threadIdx.x;
    const int w   = tid >> 6;        // wave 0..15
    const int lid = tid & 63;
    const int l15 = lid & 15;
    const int kg  = lid >> 4;        // quad 0..3
    const int ct  = w >> 1;          // column tile 0..7 (16 cols each)
    const int mh  = w & 1;           // row half (64 rows each)
    const int b   = blockIdx.x;

    // LN scratch aliases ps (never live simultaneously with attention scratch)
    float* part_s = (float*)ps;          // [8][128]
    float* part_q = part_s + 1024;       // [8][128]
    float* mean_s = part_s + 2048;       // [128]
    float* rstd_s = mean_s + 128;        // [128]

    // ---- stage x[b] fp32 -> xs bf16, coalesced float4 ----
    const float* xb = x + (size_t)b * 16384;
    #pragma unroll
    for (int i = 0; i < 4; ++i) {
        int e = i * 4096 + tid * 4;
        float4 v4 = *(const float4*)(xb + e);
        int row = e >> 7, col = e & 127;
        ushort4 pk;
        pk.x = f2bf(v4.x); pk.y = f2bf(v4.y); pk.z = f2bf(v4.z); pk.w = f2bf(v4.w);
        *(ushort4*)(xs + row * XS_S + col) = pk;
    }
    // additive key mask, key col = nt*16 + l15 (used in attention)
    float mreg[8];
    #pragma unroll
    for (int nt = 0; nt < 8; ++nt) mreg[nt] = mask[b * 128 + nt * 16 + l15];

    __syncthreads();

    for (int l = 0; l < 2; ++l) {
        // ===== Phase A: QKV projection. Wave (ct,mh): q/k/v col-tile ct, ====
        // ===== rows mh*64..+63. A-frags shared across the 3 outputs.     ====
        {
            bf16x8 bw[3][4];
            float bias[3];
            #pragma unroll
            for (int i = 0; i < 3; ++i) {
                int nrow = l * 384 + i * 128 + ct * 16 + l15;  // i: 0=q 1=k 2=v
                #pragma unroll
                for (int ks = 0; ks < 4; ++ks)
                    bw[i][ks] = *(const bf16x8*)(w_inp + (size_t)nrow * 128 + ks * 32 + kg * 8);
                bias[i] = inp_b[nrow];
            }
            #pragma unroll
            for (int mt = 0; mt < 4; ++mt) {
                const int row = mh * 64 + mt * 16;
                bf16x8 ax[4];
                #pragma unroll
                for (int ks = 0; ks < 4; ++ks)
                    ax[ks] = *(const bf16x8*)(xs + (row + l15) * XS_S + ks * 32 + kg * 8);
                #pragma unroll
                for (int i = 0; i < 3; ++i) {
                    fx4 acc = {bias[i], bias[i], bias[i], bias[i]};
                    #pragma unroll
                    for (int ks = 0; ks < 4; ++ks) acc = MFMA16(ax[ks], bw[i][ks], acc);
                    if (i < 2) {                        // q cols 0..127 | k cols 128..255
                        int colb = i * 128 + ct * 16 + l15;
                        #pragma unroll
                        for (int r = 0; r < 4; ++r)
                            qk[(row + kg * 4 + r) * QK_S + colb] = f2bf(acc[r]);
                    } else {                            // v -> transposed vT[d][t]
                        ushort4 pk;
                        pk.x = f2bf(acc[0]); pk.y = f2bf(acc[1]);
                        pk.z = f2bf(acc[2]); pk.w = f2bf(acc[3]);
                        *(ushort4*)(vt + (ct * 16 + l15) * VT_S + row + kg * 4) = pk;
                    }
                }
            }
        }
        __syncthreads();

        // ===== Phase B: attention. Wave = (head h=ct, row-half mh). =========
        {
            const int h = ct;
            unsigned short* psw = ps + w * (16 * PS_S);
            #pragma unroll
            for (int mt = 0; mt < 4; ++mt) {
                const int qrow = (mh * 4 + mt) * 16;
                // scores S[16 x 128] via K=32 MFMA, k=16..31 zero-padded
                bf16x8 aq = {};
                if (kg < 2) aq = *(const bf16x8*)(qk + (qrow + l15) * QK_S + h * 16 + kg * 8);
                fx4 sc[8];
                #pragma unroll
                for (int nt = 0; nt < 8; ++nt) {
                    bf16x8 bk = {};
                    if (kg < 2) bk = *(const bf16x8*)(qk + (nt * 16 + l15) * QK_S + 128 + h * 16 + kg * 8);
                    fx4 z = {0.f, 0.f, 0.f, 0.f};
                    sc[nt] = MFMA16(aq, bk, z);
                }
                // scale + mask + softmax over keys (in-lane nt + 16-lane group)
                float mx[4], sm[4];
                #pragma unroll
                for (int r = 0; r < 4; ++r) mx[r] = -3.0e38f;
                #pragma unroll
                for (int nt = 0; nt < 8; ++nt)
                    #pragma unroll
                    for (int r = 0; r < 4; ++r) {
                        float v = sc[nt][r] * 0.25f + mreg[nt];
                        sc[nt][r] = v;
                        mx[r] = fmaxf(mx[r], v);
                    }
                #pragma unroll
                for (int s = 1; s < 16; s <<= 1)
                    #pragma unroll
                    for (int r = 0; r < 4; ++r) mx[r] = fmaxf(mx[r], __shfl_xor(mx[r], s, 64));
                #pragma unroll
                for (int r = 0; r < 4; ++r) sm[r] = 0.f;
                #pragma unroll
                for (int nt = 0; nt < 8; ++nt)
                    #pragma unroll
                    for (int r = 0; r < 4; ++r) {
                        float e = __expf(sc[nt][r] - mx[r]);
                        sc[nt][r] = e;
                        sm[r] += e;
                    }
                #pragma unroll
                for (int s = 1; s < 16; s <<= 1)
                    #pragma unroll
                    for (int r = 0; r < 4; ++r) sm[r] += __shfl_xor(sm[r], s, 64);
                float inv[4];
                #pragma unroll
                for (int r = 0; r < 4; ++r) inv[r] = 1.f / sm[r];

                // P -> LDS (C-layout -> A-layout) in 32-key chunks, then PV
                fx4 oacc = {0.f, 0.f, 0.f, 0.f};
                #pragma unroll
                for (int c = 0; c < 4; ++c) {
                    #pragma unroll
                    for (int f = 0; f < 2; ++f) {
                        int nt = c * 2 + f;
                        #pragma unroll
                        for (int r = 0; r < 4; ++r)
                            psw[(kg * 4 + r) * PS_S + f * 16 + l15] =
                                f2bf(sc[nt][r] * inv[r]);
                    }
                    asm volatile("s_waitcnt lgkmcnt(0)" ::: "memory");  // own-wave RAW
                    bf16x8 ap = *(const bf16x8*)(psw + l15 * PS_S + kg * 8);
                    bf16x8 bv = *(const bf16x8*)(vt + (h * 16 + l15) * VT_S + c * 32 + kg * 8);
                    oacc = MFMA16(ap, bv, oacc);
                }
                // o_h overwrites this wave's own q block (rows qrow.., cols h*16..)
                #pragma unroll
                for (int r = 0; r < 4; ++r)
                    qk[(qrow + kg * 4 + r) * QK_S + h * 16 + l15] = f2bf(oacc[r]);
            }
        }
        __syncthreads();

        // ===== Phase C: out-proj + bias + residual + LayerNorm1 =============
        {
            const int col = ct * 16 + l15;
            bf16x8 bw[4];
            #pragma unroll
            for (int ks = 0; ks < 4; ++ks)
                bw[ks] = *(const bf16x8*)(w_out + (size_t)(l * 128 + col) * 128 + ks * 32 + kg * 8);
            fx4 acc[4];
            #pragma unroll
            for (int mt = 0; mt < 4; ++mt) {
                const int row = mh * 64 + mt * 16;
                fx4 a = {0.f, 0.f, 0.f, 0.f};
                #pragma unroll
                for (int ks = 0; ks < 4; ++ks) {
                    bf16x8 af = *(const bf16x8*)(qk + (row + l15) * QK_S + ks * 32 + kg * 8);
                    a = MFMA16(af, bw[ks], a);
                }
                acc[mt] = a;
            }
            float ob = out_b[l * 128 + col];
            #pragma unroll
            for (int mt = 0; mt < 4; ++mt)
                #pragma unroll
                for (int r = 0; r < 4; ++r)
                    acc[mt][r] += ob + bf2f(xs[(mh * 64 + mt * 16 + kg * 4 + r) * XS_S + col]);
            // per-wave 16-col partial sums -> LDS; combine by 128 threads
            #pragma unroll
            for (int mt = 0; mt < 4; ++mt) {
                fx4 s = acc[mt], q;
                #pragma unroll
                for (int r = 0; r < 4; ++r) q[r] = s[r] * s[r];
                #pragma unroll
                for (int st = 1; st < 16; st <<= 1)
                    #pragma unroll
                    for (int r = 0; r < 4; ++r) {
                        s[r] += __shfl_xor(s[r], st, 64);
                        q[r] += __shfl_xor(q[r], st, 64);
                    }
                if (l15 == 0) {
                    *(fx4*)(part_s + ct * 128 + mh * 64 + mt * 16 + kg * 4) = s;
                    *(fx4*)(part_q + ct * 128 + mh * 64 + mt * 16 + kg * 4) = q;
                }
            }
            __syncthreads();
            if (tid < 128) {
                float ms = 0.f, mq = 0.f;
                #pragma unroll
                for (int g = 0; g < 8; ++g) {
                    ms += part_s[g * 128 + tid];
                    mq += part_q[g * 128 + tid];
                }
                float mean = ms * 0.0078125f;
                float var  = mq * 0.0078125f - mean * mean;
                mean_s[tid] = mean;
                rstd_s[tid] = rsqrtf(var + 1e-5f);
            }
            __syncthreads();
            float g = ln1g[l * 128 + col], bb = ln1b[l * 128 + col];
            #pragma unroll
            for (int mt = 0; mt < 4; ++mt)
                #pragma unroll
                for (int r = 0; r < 4; ++r) {
                    int row = mh * 64 + mt * 16 + kg * 4 + r;
                    float v = (acc[mt][r] - mean_s[row]) * rstd_s[row] * g + bb;
                    xs[row * XS_S + col] = f2bf(v);
                }
        }
        __syncthreads();

        // ===== Phase D: FF in 4 K-chunks of 128; hidden staged in vt ========
        fx4 yacc[4];
        {
            fx4 zz = {0.f, 0.f, 0.f, 0.f};
            #pragma unroll
            for (int mt = 0; mt < 4; ++mt) yacc[mt] = zz;
        }
        for (int c = 0; c < 4; ++c) {
            {   // FF1 chunk + bias + relu -> vt
                const int nrow = l * 512 + c * 128 + ct * 16 + l15;
                bf16x8 b1[4];
                #pragma unroll
                for (int ks = 0; ks < 4; ++ks)
                    b1[ks] = *(const bf16x8*)(w_ff1 + (size_t)nrow * 128 + ks * 32 + kg * 8);
                float f1 = ff1b[nrow];
                #pragma unroll
                for (int mt = 0; mt < 4; ++mt) {
                    const int row = mh * 64 + mt * 16;
                    fx4 a = {f1, f1, f1, f1};
                    #pragma unroll
                    for (int ks = 0; ks < 4; ++ks) {
                        bf16x8 ax = *(const bf16x8*)(xs + (row + l15) * XS_S + ks * 32 + kg * 8);
                        a = MFMA16(ax, b1[ks], a);
                    }
                    #pragma unroll
                    for (int r = 0; r < 4; ++r)
                        vt[(row + kg * 4 + r) * VT_S + ct * 16 + l15] = f2bf(fmaxf(a[r], 0.f));
                }
            }
            __syncthreads();
            {   // FF2 partial accumulate
                bf16x8 b2[4];
                #pragma unroll
                for (int ks = 0; ks < 4; ++ks)
                    b2[ks] = *(const bf16x8*)(w_ff2 + (size_t)(l * 128 + ct * 16 + l15) * 512
                                              + c * 128 + ks * 32 + kg * 8);
                #pragma unroll
                for (int mt = 0; mt < 4; ++mt) {
                    const int row = mh * 64 + mt * 16;
                    #pragma unroll
                    for (int ks = 0; ks < 4; ++ks) {
                        bf16x8 ah = *(const bf16x8*)(vt + (row + l15) * VT_S + ks * 32 + kg * 8);
                        yacc[mt] = MFMA16(ah, b2[ks], yacc[mt]);
                    }
                }
            }
            __syncthreads();
        }

        // ===== Phase E: + bias + residual + LayerNorm2 (+ final output) =====
        {
            const int col = ct * 16 + l15;
            float fb = ff2b[l * 128 + col];
            #pragma unroll
            for (int mt = 0; mt < 4; ++mt)
                #pragma unroll
                for (int r = 0; r < 4; ++r)
                    yacc[mt][r] += fb + bf2f(xs[(mh * 64 + mt * 16 + kg * 4 + r) * XS_S + col]);
            #pragma unroll
            for (int mt = 0; mt < 4; ++mt) {
                fx4 s = yacc[mt], q;
                #pragma unroll
                for (int r = 0; r < 4; ++r) q[r] = s[r] * s[r];
                #pragma unroll
                for (int st = 1; st < 16; st <<= 1)
                    #pragma unroll
                    for (int r = 0; r < 4; ++r) {
                        s[r] += __shfl_xor(s[r], st, 64);
                        q[r] += __shfl_xor(q[r], st, 64);
                    }
                if (l15 == 0) {
                    *(fx4*)(part_s + ct * 128 + mh * 64 + mt * 16 + kg * 4) = s;
                    *(fx4*)(part_q + ct * 128 + mh * 64 + mt * 16 + kg * 4) = q;
                }
            }
            __syncthreads();
            if (tid < 128) {
                float ms = 0.f, mq = 0.f;
                #pragma unroll
                for (int g = 0; g < 8; ++g) {
                    ms += part_s[g * 128 + tid];
                    mq += part_q[g * 128 + tid];
                }
                float mean = ms * 0.0078125f;
                float var  = mq * 0.0078125f - mean * mean;
                mean_s[tid] = mean;
                rstd_s[tid] = rsqrtf(var + 1e-5f);
            }
            __syncthreads();
            float g = ln2g[l * 128 + col], bb = ln2b[l * 128 + col];
            if (l == 1) {   // final: fp32 output
                float* ob = out + (size_t)b * 16384;
                #pragma unroll
                for (int mt = 0; mt < 4; ++mt)
                    #pragma unroll
                    for (int r = 0; r < 4; ++r) {
                        int row = mh * 64 + mt * 16 + kg * 4 + r;
                        ob[row * 128 + col] = (yacc[mt][r] - mean_s[row]) * rstd_s[row] * g + bb;
                    }
            } else {
                #pragma unroll
                for (int mt = 0; mt < 4; ++mt)
                    #pragma unroll
                    for (int r = 0; r < 4; ++r) {
                        int row = mh * 64 + mt * 16 + kg * 4 + r;
                        float v = (yacc[mt][r] - mean_s[row]) * rstd_s[row] * g + bb;
                        xs[row * XS_S + col] = f2bf(v);
                    }
            }
        }
        __syncthreads();
    }
}

// --------------------------------------------------------------------------
extern "C" void kernel_launch(void* const* d_in, const int* in_sizes, int n_in,
                              void* d_out, int out_size, void* d_ws, size_t ws_size,
                              hipStream_t stream) {
    const float* x    = (const float*)d_in[0];
    const float* mask = (const float*)d_in[1];
    const float* w_in = (const float*)d_in[2];
    const float* b_in = (const float*)d_in[3];
    const float* w_o  = (const float*)d_in[4];
    const float* b_o  = (const float*)d_in[5];
    const float* g1   = (const float*)d_in[6];
    const float* bb1  = (const float*)d_in[7];
    const float* w1   = (const float*)d_in[8];
    const float* b1   = (const float*)d_in[9];
    const float* w2   = (const float*)d_in[10];
    const float* b2   = (const float*)d_in[11];
    const float* g2   = (const float*)d_in[12];
    const float* bb2  = (const float*)d_in[13];

    unsigned short* ws = (unsigned short*)d_ws;   // bf16 weights, 786432 B
    prep_weights_bf16<<<384, 256, 0, stream>>>(w_in, w_o, w1, w2, ws);
    fused_transformer<<<1024, 1024, 0, stream>>>(
        x, mask, b_in, b_o, g1, bb1, b1, b2, g2, bb2,
        ws,                 // in_proj  [L][384][128]
        ws + 98304,         // out_w    [L][128][128]
        ws + 131072,        // ff1_w    [L][512][128]
        ws + 262144,        // ff2_w    [L][128][512]
        (float*)d_out);
}